// Round 7
// baseline (1129.658 us; speedup 1.0000x reference)
//
#include <hip/hip_runtime.h>
#include <hip/hip_bf16.h>

// Problem constants (fixed by the reference).
constexpr int T  = 4096;   // contraction dim (K = t)
constexpr int Bb = 8;      // batch
constexpr int C  = 512;    // channels (N)
constexpr int S  = 2048;   // groups (M)
constexpr int BC = Bb * C; // 4096 floats: t-row stride of x, s-row stride of out

constexpr int BK = 32;        // K-tile staged per iteration
constexpr int NK = T / BK;    // 128 iterations

typedef __bf16 bf16x8 __attribute__((ext_vector_type(8)));
typedef float  f32x16 __attribute__((ext_vector_type(16)));
typedef float  f32x4  __attribute__((ext_vector_type(4)));

// pack two f32 -> one dword of 2x bf16 (lo = first, hi = second), RNE.
__device__ inline unsigned pk2(float lo, float hi) {
    union { __hip_bfloat16 h; unsigned short u; } a, b;
    a.h = __float2bfloat16(lo);
    b.h = __float2bfloat16(hi);
    return ((unsigned)b.u << 16) | (unsigned)a.u;
}

// 16B-slot swizzle, bijective within each 32-slot group; spreads the strided
// staging writes across bank groups while fragment reads stay a lane-permuted
// contiguous region (conflict-free b128, verified r4-r6 low conflict counts).
__device__ inline int slot16(int s) { return s ^ ((s >> 2) & 7); }

// out[0,b,c] = leftmost[c]
__global__ void left_fill(const float* __restrict__ left, float* __restrict__ out) {
    int i = blockIdx.x * blockDim.x + threadIdx.x;   // 0..BC-1
    if (i < BC) out[i] = left[i & (C - 1)];
}

// Per-b GEMM: out[(s+1),b,c] = sum_t mask[b,t,s] * x[t,b,c].
// Block 256 thr = 4 waves (2m x 2n), tile 128(s) x 64(c), wave tile 64x32,
// BK=32, dbuf LDS (24KB). Grid 1024 = 4 blocks/CU (whole grid resident):
// 4 independent barrier domains per CU vs 2 in r4-r6.
// DEPTH-2 register prefetch: two load sets La/Lb, loop 2x-unrolled; a tile's
// global loads are consumed (vmcnt-waited) two half-iterations + 2 barriers
// after issue (~1400 cyc cover vs ~900 cyc HBM latency).
// Staging (wave-aligned roles): waves 0-1 stage mask (A), wave 2 stages x (B),
// wave 3 compute-only. LDS (bf16): A = oct*2048B + slot16(s)*16B + (t&7)*2B,
// B at +8192 = oct*1024B + slot16(c)*16B + (t&7)*2B; buf stride 12KB.
__global__ __launch_bounds__(256, 4) void ds_gemm(
    const float* __restrict__ x,
    const float* __restrict__ mask,
    float* __restrict__ out)
{
    __shared__ __align__(16) unsigned char smem[24576];  // 2 bufs x (8KB A | 4KB B)

    const int bid = blockIdx.x;
    const int mt  = bid & 15;        // s-tile (fastest)
    const int nt  = (bid >> 4) & 7;  // c-tile
    const int b   = bid >> 7;        // batch (slowest)

    const int tid  = threadIdx.x;
    const int lane = tid & 63;
    const int wave = tid >> 6;       // 0..3
    const int wm = wave >> 1;        // s-half (0..1)
    const int wn = wave & 1;         // c-half (0..1)
    const int lm = lane & 31;
    const int kg = lane >> 5;

    // ---------------- staging roles (wave-aligned, no intra-wave divergence)
    // role 0 (tid 0-127, waves 0-1): A = mask tile 128s x 32t, 8 f32x4 loads
    // role 1 (tid 128-191, wave 2):  B = x    tile  64c x 32t, 8 f32x4 loads
    // role 2 (tid 192-255, wave 3):  compute-only
    const int  role = (tid < 128) ? 0 : (tid < 192 ? 1 : 2);
    const int  ii   = (role == 0) ? tid : (tid - 128);
    const int  sg   = (role == 0) ? (ii & 31) : (ii & 15);  // 4-wide col group
    const int  tg   = (role == 0) ? (ii >> 5) : ((ii >> 4) & 3);  // t-oct 0..3

    const float* gsrc = (role == 0)
        ? mask + (size_t)b * T * S + (size_t)(tg * 8) * S + mt * 128 + sg * 4
        : x    + (size_t)(tg * 8) * BC + b * C + nt * 64 + sg * 4;
    const size_t grow  = (role == 0) ? (size_t)S : (size_t)BC;  // floats per t-row
    const size_t gstep = grow * BK;                              // advance per K-tile

    int waddr[4];
#pragma unroll
    for (int j = 0; j < 4; ++j)
        waddr[j] = ((role == 0) ? tg * 2048 : 8192 + tg * 1024) + slot16(sg * 4 + j) * 16;

    // ---------------- fragment read addresses (oct = kk*2 + kg)
    int raddrA[2][2], raddrB[2];
#pragma unroll
    for (int kk = 0; kk < 2; ++kk) {
#pragma unroll
        for (int q = 0; q < 2; ++q)
            raddrA[kk][q] = (kk * 2 + kg) * 2048 + slot16(wm * 64 + q * 32 + lm) * 16;
        raddrB[kk] = 8192 + (kk * 2 + kg) * 1024 + slot16(wn * 32 + lm) * 16;
    }

    f32x16 acc[2] = {};
    f32x4  La[8], Lb[8];   // depth-2 staging register sets

#define LOAD_TILE(Lr, k)                                                    \
    if (role < 2) {                                                         \
        const float* p_ = gsrc + (size_t)(k) * gstep;                       \
        _Pragma("unroll") for (int r = 0; r < 8; ++r)                       \
            Lr[r] = *(const f32x4*)(p_ + (size_t)r * grow);                 \
    }

#define WRITE_TILE(Lr, buf)                                                 \
    if (role < 2) {                                                         \
        const int boff_ = (buf) * 12288;                                    \
        _Pragma("unroll") for (int j = 0; j < 4; ++j) {                     \
            uint4 w_;                                                       \
            w_.x = pk2(Lr[0][j], Lr[1][j]);                                 \
            w_.y = pk2(Lr[2][j], Lr[3][j]);                                 \
            w_.z = pk2(Lr[4][j], Lr[5][j]);                                 \
            w_.w = pk2(Lr[6][j], Lr[7][j]);                                 \
            *(uint4*)(smem + boff_ + waddr[j]) = w_;                        \
        }                                                                   \
    }

#define COMPUTE(buf)                                                        \
    {                                                                       \
        const int boff_ = (buf) * 12288;                                    \
        _Pragma("unroll") for (int kk = 0; kk < 2; ++kk) {                  \
            bf16x8 a0_ = *(const bf16x8*)(smem + boff_ + raddrA[kk][0]);    \
            bf16x8 a1_ = *(const bf16x8*)(smem + boff_ + raddrA[kk][1]);    \
            bf16x8 b0_ = *(const bf16x8*)(smem + boff_ + raddrB[kk]);       \
            acc[0] = __builtin_amdgcn_mfma_f32_32x32x16_bf16(a0_, b0_, acc[0], 0, 0, 0); \
            acc[1] = __builtin_amdgcn_mfma_f32_32x32x16_bf16(a1_, b0_, acc[1], 0, 0, 0); \
        }                                                                   \
    }

    // Prologue: two tiles in flight.
    LOAD_TILE(La, 0);
    LOAD_TILE(Lb, 1);

    for (int k = 0; k < NK; k += 2) {
        // half-iter A: consume La (loaded at k-2 wrt this point's schedule)
        WRITE_TILE(La, 0);                    // counted vmcnt wait: ~2 iters of cover
        if (k + 2 < NK) LOAD_TILE(La, k + 2);
        __syncthreads();
        COMPUTE(0);
        // half-iter B
        WRITE_TILE(Lb, 1);                    // buf1 last read 1 barrier ago -> safe
        if (k + 3 < NK) LOAD_TILE(Lb, k + 3);
        __syncthreads();
        COMPUTE(1);
    }

#undef LOAD_TILE
#undef WRITE_TILE
#undef COMPUTE

    // Epilogue. C/D layout (HW-verified): col = lane&31, row = (r&3)+8*(r>>2)+4*(lane>>5).
    const int s_w  = mt * 128 + wm * 64;
    const int ccol = nt * 64 + wn * 32 + lm;
    float* outp = out + BC;   // skip leftmost row
#pragma unroll
    for (int m2 = 0; m2 < 2; ++m2) {
#pragma unroll
        for (int r = 0; r < 16; ++r) {
            const int row  = (r & 3) + 8 * (r >> 2) + 4 * kg;
            const int srow = s_w + m2 * 32 + row;
            outp[(size_t)srow * BC + b * C + ccol] = acc[m2][r];
        }
    }
}

extern "C" void kernel_launch(void* const* d_in, const int* in_sizes, int n_in,
                              void* d_out, int out_size, void* d_ws, size_t ws_size,
                              hipStream_t stream) {
    const float* x    = (const float*)d_in[0];  // [T,B,C] fp32
    const float* mask = (const float*)d_in[1];  // [B,T,S] fp32
    // d_in[2] = size_of_groups (int64) — unused by the 'average' reference path
    const float* left = (const float*)d_in[3];  // [1,1,C] fp32
    float* out = (float*)d_out;                 // [S+1,B,C] fp32

    left_fill<<<BC / 256, 256, 0, stream>>>(left, out);
    ds_gemm<<<Bb * (C / 64) * (S / 128), 256, 0, stream>>>(x, mask, out);
}

// Round 8
// 142.019 us; speedup vs baseline: 7.9543x; 7.9543x over previous
//
#include <hip/hip_runtime.h>
#include <hip/hip_bf16.h>

// Problem constants (fixed by the reference).
constexpr int T  = 4096;   // contraction dim (K = t)
constexpr int Bb = 8;      // batch
constexpr int C  = 512;    // channels (N)
constexpr int S  = 2048;   // groups (M)
constexpr int BC = Bb * C; // 4096 floats: t-row stride of x, s-row stride of out

constexpr int BK = 64;        // K-tile staged per iteration
constexpr int NK = T / BK;    // 64 iterations

typedef __bf16 bf16x8 __attribute__((ext_vector_type(8)));
typedef float  f32x16 __attribute__((ext_vector_type(16)));
typedef float  f32x4  __attribute__((ext_vector_type(4)));

// pack two f32 -> one dword of 2x bf16 (lo = first, hi = second), RNE.
__device__ inline unsigned pk2(float lo, float hi) {
    union { __hip_bfloat16 h; unsigned short u; } a, b;
    a.h = __float2bfloat16(lo);
    b.h = __float2bfloat16(hi);
    return ((unsigned)b.u << 16) | (unsigned)a.u;
}

// 16B-slot swizzle, bijective within each 32-slot group; spreads the
// strided staging writes across bank groups while fragment reads stay a
// lane-permuted contiguous 512B region (conflict-free b128).
__device__ inline int slot16(int s) { return s ^ ((s >> 2) & 7); }

// out[0,b,c] = leftmost[c]
__global__ void left_fill(const float* __restrict__ left, float* __restrict__ out) {
    int i = blockIdx.x * blockDim.x + threadIdx.x;   // 0..BC-1
    if (i < BC) out[i] = left[i & (C - 1)];
}

// Per-b GEMM: out[(s+1),b,c] = sum_t mask[b,t,s] * x[t,b,c].
// IDENTICAL compute structure to round 6 (163 us): block 512 thr = 8 waves,
// tile 128(s) x 128(c), BK=64, dbuf LDS (64KB), within-block split-K
// (K-group h = wave>>2 consumes t-octs h*4..h*4+3; 1:1 ds_read:MFMA),
// loop W(k)[vmcnt wait] -> issue(k+1) -> barrier -> COMPUTE(k).
//
// ROUND-8 CHANGE (one lever): chunked XCD work swizzle. HW dispatches
// consecutive blockIdx round-robin across the 8 XCDs (xcd = bid%8, perf
// heuristic only -- correctness never depends on it). Remap so XCD i owns
// work-ids [i*64, (i+1)*64) = the ENTIRE (mt,nt) plane of batch b=i.
// Then mask-panel re-reads (shared by 4 nt-blocks) AND x-panel re-reads
// (shared by 16 mt-blocks) are served by the SAME XCD's L2: per-XCD
// per-K-iter working set = 512KB mask + 128KB x << 4MB L2. Without this,
// the 16 mt-sharers of each x panel sit on all 8 XCDs and ~2GB of tile
// re-reads mix L2/L3/HBM service (the r4-r6 160us plateau).
__global__ __launch_bounds__(512, 4) void ds_gemm(
    const float* __restrict__ x,
    const float* __restrict__ mask,
    float* __restrict__ out)
{
    __shared__ __align__(16) unsigned char smem[65536];  // 2 bufs x (16KB A | 16KB B)

    // ---- chunked XCD swizzle (bijective: 512 = 8 xcd * 64 slots) ----
    const int bid0 = blockIdx.x;
    const int xcd  = bid0 & 7;            // HW XCD of this block (round-robin)
    const int slot = bid0 >> 3;           // 0..63 within this XCD
    const int b    = xcd;                 // batch plane owned by this XCD
    const int mt   = slot & 15;           // s-tile
    const int nt   = (slot >> 4) & 3;     // c-tile
    // first-resident 32 blocks/XCD = mt 0-15 x nt 0-1: every mask panel has
    // both nt-sharers and every x panel all 16 mt-sharers co-resident.

    const int tid  = threadIdx.x;
    const int lane = tid & 63;
    const int wave = tid >> 6;       // 0..7
    const int h    = wave >> 2;      // K-group (0..1)
    const int wq   = wave & 3;
    const int wm = wq >> 1;          // s-half (0..1)
    const int wn = wq & 1;           // c-half (0..1)
    const int lm = lane & 31;
    const int kg = lane >> 5;

    // ---------------- staging role: threads 0-255 stage A(mask), 256-511 B(x)
    // Each thread: one t-oct (8 rows) x 4 cols -> 8 global f32x4 loads,
    // packed into 4x ds_write_b128 (8 bf16 t-values per 16B col slot).
    const int  ii  = tid & 255;
    const int  sg  = ii & 31;        // 4-wide col group within 128-wide tile
    const int  tg  = ii >> 5;        // t-oct 0..7 within the K-tile
    const bool stB = (tid >= 256);

    const float* gsrc = stB
        ? x    + (size_t)(tg * 8) * BC + b * C + nt * 128 + sg * 4
        : mask + (size_t)b * T * S + (size_t)(tg * 8) * S + mt * 128 + sg * 4;
    const size_t grow  = stB ? (size_t)BC : (size_t)S;  // floats per t-row
    const size_t gstep = grow * BK;                      // advance per K-tile

    int waddr[4];
#pragma unroll
    for (int j = 0; j < 4; ++j)
        waddr[j] = (stB ? 16384 : 0) + tg * 2048 + slot16(sg * 4 + j) * 16;

    // ---------------- fragment read addresses (oct = h*4 + kk*2 + kg)
    int raddrA[2][2], raddrB[2][2];
#pragma unroll
    for (int kk = 0; kk < 2; ++kk)
#pragma unroll
        for (int q = 0; q < 2; ++q) {
            const int oct = h * 4 + kk * 2 + kg;
            raddrA[kk][q] = oct * 2048 + slot16(wm * 64 + q * 32 + lm) * 16;
            raddrB[kk][q] = 16384 + oct * 2048 + slot16(wn * 64 + q * 32 + lm) * 16;
        }

    f32x16 acc[2][2] = {};
    f32x4  L[8];

#define LOAD_TILE(k)                                                        \
    {                                                                       \
        const float* p_ = gsrc + (size_t)(k) * gstep;                       \
        _Pragma("unroll") for (int r = 0; r < 8; ++r)                       \
            L[r] = *(const f32x4*)(p_ + (size_t)r * grow);                  \
    }

#define WRITE_TILE(buf)                                                     \
    {                                                                       \
        const int boff_ = (buf) * 32768;                                    \
        _Pragma("unroll") for (int j = 0; j < 4; ++j) {                     \
            uint4 w_;                                                       \
            w_.x = pk2(L[0][j], L[1][j]);                                   \
            w_.y = pk2(L[2][j], L[3][j]);                                   \
            w_.z = pk2(L[4][j], L[5][j]);                                   \
            w_.w = pk2(L[6][j], L[7][j]);                                   \
            *(uint4*)(smem + boff_ + waddr[j]) = w_;                        \
        }                                                                   \
    }

#define COMPUTE(buf)                                                        \
    {                                                                       \
        const int boff_ = (buf) * 32768;                                    \
        _Pragma("unroll") for (int kk = 0; kk < 2; ++kk) {                  \
            bf16x8 a0_ = *(const bf16x8*)(smem + boff_ + raddrA[kk][0]);    \
            bf16x8 a1_ = *(const bf16x8*)(smem + boff_ + raddrA[kk][1]);    \
            bf16x8 b0_ = *(const bf16x8*)(smem + boff_ + raddrB[kk][0]);    \
            bf16x8 b1_ = *(const bf16x8*)(smem + boff_ + raddrB[kk][1]);    \
            acc[0][0] = __builtin_amdgcn_mfma_f32_32x32x16_bf16(a0_, b0_, acc[0][0], 0, 0, 0); \
            acc[0][1] = __builtin_amdgcn_mfma_f32_32x32x16_bf16(a0_, b1_, acc[0][1], 0, 0, 0); \
            acc[1][0] = __builtin_amdgcn_mfma_f32_32x32x16_bf16(a1_, b0_, acc[1][0], 0, 0, 0); \
            acc[1][1] = __builtin_amdgcn_mfma_f32_32x32x16_bf16(a1_, b1_, acc[1][1], 0, 0, 0); \
        }                                                                   \
    }

    // Prologue: issue loads for tile 0.
    LOAD_TILE(0);

    for (int k = 0; k < NK; ++k) {
        WRITE_TILE(k & 1);            // vmcnt wait lands here (issued a full iter ago)
        if (k + 1 < NK) LOAD_TILE(k + 1);
        __syncthreads();              // staged tile visible to all waves
        COMPUTE(k & 1);
        // W(k+1) overwrites buf (k+1)&1, last read in COMPUTE(k-1);
        // barrier(k) sits between them -> single barrier per iter is safe.
    }

#undef LOAD_TILE
#undef WRITE_TILE
#undef COMPUTE

    // -------- cross-K-group reduction via LDS, then store (K-group 0 only).
    // Wave w (K-group 1) stores at region (w-4)*16KB; layout: frag(m2,n2)
    // block 4KB, r-quad 1KB, lane*16B -> stride-1 float4 (conflict-free).
    __syncthreads();                 // main-loop LDS reads done; safe to reuse
    if (h == 1) {
#pragma unroll
        for (int m2 = 0; m2 < 2; ++m2)
#pragma unroll
            for (int n2 = 0; n2 < 2; ++n2) {
                unsigned char* base = smem + (wave - 4) * 16384 + (m2 * 2 + n2) * 4096 + lane * 16;
#pragma unroll
                for (int r4 = 0; r4 < 4; ++r4) {
                    f32x4 v = { acc[m2][n2][r4 * 4 + 0], acc[m2][n2][r4 * 4 + 1],
                                acc[m2][n2][r4 * 4 + 2], acc[m2][n2][r4 * 4 + 3] };
                    *(f32x4*)(base + r4 * 1024) = v;
                }
            }
    }
    __syncthreads();
    if (h == 0) {
#pragma unroll
        for (int m2 = 0; m2 < 2; ++m2)
#pragma unroll
            for (int n2 = 0; n2 < 2; ++n2) {
                const unsigned char* base = smem + wave * 16384 + (m2 * 2 + n2) * 4096 + lane * 16;
#pragma unroll
                for (int r4 = 0; r4 < 4; ++r4) {
                    f32x4 v = *(const f32x4*)(base + r4 * 1024);
#pragma unroll
                    for (int j = 0; j < 4; ++j) acc[m2][n2][r4 * 4 + j] += v[j];
                }
            }

        // Store. C/D layout (HW-verified): col = lane&31,
        // row = (r&3) + 8*(r>>2) + 4*(lane>>5).
        const int s_w = mt * 128 + wm * 64;
        const int c_w = nt * 128 + wn * 64;
        float* outp = out + BC;   // skip leftmost row
#pragma unroll
        for (int m2 = 0; m2 < 2; ++m2)
#pragma unroll
            for (int n2 = 0; n2 < 2; ++n2)
#pragma unroll
                for (int r = 0; r < 16; ++r) {
                    const int row  = (r & 3) + 8 * (r >> 2) + 4 * kg;
                    const int srow = s_w + m2 * 32 + row;
                    const int ccol = c_w + n2 * 32 + lm;
                    outp[(size_t)srow * BC + b * C + ccol] = acc[m2][n2][r];
                }
    }
}

extern "C" void kernel_launch(void* const* d_in, const int* in_sizes, int n_in,
                              void* d_out, int out_size, void* d_ws, size_t ws_size,
                              hipStream_t stream) {
    const float* x    = (const float*)d_in[0];  // [T,B,C] fp32
    const float* mask = (const float*)d_in[1];  // [B,T,S] fp32
    // d_in[2] = size_of_groups (int64) — unused by the 'average' reference path
    const float* left = (const float*)d_in[3];  // [1,1,C] fp32
    float* out = (float*)d_out;                 // [S+1,B,C] fp32

    left_fill<<<BC / 256, 256, 0, stream>>>(left, out);
    ds_gemm<<<Bb * (S / 128) * (C / 128), 512, 0, stream>>>(x, mask, out);
}